// Round 1
// baseline (259.317 us; speedup 1.0000x reference)
//
#include <hip/hip_runtime.h>
#include <hip/hip_bf16.h>
#include <cstdint>
#include <cstddef>

// Problem constants
#define BDIM 2
#define SDIM 2048
#define DDIM 1024
#define HN   16
#define HDIM 64

using bf16 = __bf16;
typedef __attribute__((ext_vector_type(8))) __bf16 bf16x8;
typedef __attribute__((ext_vector_type(4))) float  f32x4;

#define MFMA16(a, b, c) __builtin_amdgcn_mfma_f32_16x16x32_bf16((a), (b), (c), 0, 0, 0)

#define ASYNC16(g, l)                                                          \
  __builtin_amdgcn_global_load_lds(                                            \
      (const __attribute__((address_space(1))) void*)(g),                      \
      (__attribute__((address_space(3))) void*)(l), 16, 0, 0)

// ---------------------------------------------------------------- conversions
__global__ __launch_bounds__(256) void cvt_bf16(const float* __restrict__ src,
                                                bf16* __restrict__ dst, int n4) {
  int i = blockIdx.x * 256 + threadIdx.x;
  if (i < n4) {
    float4 v = ((const float4*)src)[i];
    typedef __attribute__((ext_vector_type(4))) __bf16 bf16x4;
    bf16x4 o = {(__bf16)v.x, (__bf16)v.y, (__bf16)v.z, (__bf16)v.w};
    *(bf16x4*)(dst + (size_t)i * 4) = o;
  }
}

// ---------------------------------------------------------------- rope table
__global__ __launch_bounds__(256) void rope_table(float* __restrict__ cosT,
                                                  float* __restrict__ sinT) {
  int i = blockIdx.x * 256 + threadIdx.x;  // SDIM*32 threads
  int s = i >> 5, j = i & 31;
  float inv = powf(10000.f, -(float)j * (1.f / 32.f));
  float a = (float)s * inv;
  float sn, c;
  sincosf(a, &sn, &c);
  cosT[s * 64 + j]      = c;
  cosT[s * 64 + j + 32] = c;
  sinT[s * 64 + j]      = sn;
  sinT[s * 64 + j + 32] = sn;
}

// ---------------------------------------------------------------- rope apply (in-place on q and k)
__global__ __launch_bounds__(256) void rope_apply(bf16* __restrict__ q,
                                                  bf16* __restrict__ k,
                                                  const float* __restrict__ cosT,
                                                  const float* __restrict__ sinT) {
  int i = blockIdx.x * 256 + threadIdx.x;  // 32*SDIM*32 threads
  int j = i & 31;
  int s = (i >> 5) & (SDIM - 1);
  int bh = i >> 16;  // SDIM*32 == 1<<16
  size_t base = ((size_t)bh * SDIM + s) * HDIM;
  float c = cosT[s * 64 + j], sn = sinT[s * 64 + j];
  float a = (float)q[base + j], b2 = (float)q[base + j + 32];
  q[base + j]      = (__bf16)(a * c - b2 * sn);
  q[base + j + 32] = (__bf16)(b2 * c + a * sn);
  a = (float)k[base + j]; b2 = (float)k[base + j + 32];
  k[base + j]      = (__bf16)(a * c - b2 * sn);
  k[base + j + 32] = (__bf16)(b2 * c + a * sn);
}

// ---------------------------------------------------------------- GEMM  C = A * B^T
// A: [4096][1024] bf16 row-major, Bw: [1024][1024] bf16 row-major (rows = out features)
// MODE 0: write bf16 to [B][H][S][HD] (QKV), blockIdx.z selects weight/output
// MODE 1: write fp32 row-major [4096][1024]
template <int MODE>
__global__ __launch_bounds__(256) void gemm_bt(const bf16* __restrict__ A,
                                               const bf16* __restrict__ B0,
                                               void* __restrict__ C0) {
  constexpr int K = 1024;
  __shared__ __align__(16) bf16 As[128 * 64];
  __shared__ __align__(16) bf16 Bs[128 * 64];
  const int tid = threadIdx.x;
  const int l = tid & 63, w = tid >> 6;
  const int wr = w >> 1, wc = w & 1;
  const int lr = l & 15, lg = l >> 4;
  const int bm = blockIdx.y * 128;
  const int bn = blockIdx.x * 128;
  const bf16* Bw = B0 + (size_t)blockIdx.z * (1024 * 1024);

  f32x4 acc[4][4] = {};

  for (int k0 = 0; k0 < K; k0 += 64) {
    __syncthreads();
#pragma unroll
    for (int i = 0; i < 4; ++i) {
      int idx = i * 2048 + tid * 8;
      int row = idx >> 6, col = idx & 63;
      ASYNC16(A + (size_t)(bm + row) * K + (k0 + col), As + idx);
      ASYNC16(Bw + (size_t)(bn + row) * K + (k0 + col), Bs + idx);
    }
    __syncthreads();
#pragma unroll
    for (int c = 0; c < 2; ++c) {
      bf16x8 af[4], bfr[4];
#pragma unroll
      for (int m = 0; m < 4; ++m)
        af[m] = *(const bf16x8*)(As + (wr * 64 + m * 16 + lr) * 64 + c * 32 + lg * 8);
#pragma unroll
      for (int n = 0; n < 4; ++n)
        bfr[n] = *(const bf16x8*)(Bs + (wc * 64 + n * 16 + lr) * 64 + c * 32 + lg * 8);
#pragma unroll
      for (int m = 0; m < 4; ++m)
#pragma unroll
        for (int n = 0; n < 4; ++n)
          acc[m][n] = MFMA16(af[m], bfr[n], acc[m][n]);
    }
  }

#pragma unroll
  for (int m = 0; m < 4; ++m) {
#pragma unroll
    for (int n = 0; n < 4; ++n) {
#pragma unroll
      for (int r = 0; r < 4; ++r) {
        int row = bm + wr * 64 + m * 16 + lg * 4 + r;
        int col = bn + wc * 64 + n * 16 + lr;
        float v = acc[m][n][r];
        if constexpr (MODE == 0) {
          bf16* C = (bf16*)C0 + (size_t)blockIdx.z * ((size_t)BDIM * SDIM * DDIM);
          size_t off = (((size_t)(row >> 11) * HN + (col >> 6)) * SDIM + (row & (SDIM - 1))) * HDIM + (col & 63);
          C[off] = (__bf16)v;
        } else {
          ((float*)C0)[(size_t)row * DDIM + col] = v;
        }
      }
    }
  }
}

// ---------------------------------------------------------------- flash attention (causal)
// Q/K/V: [B*H][S][HD] bf16 (roped). Output: [B][S][D] bf16 row-major.
// 4 waves; wave w owns 32 q-rows (2 row-frags); KV tiles of 64 staged in LDS.
__global__ __launch_bounds__(256) void attn_fwd(const bf16* __restrict__ qg,
                                                const bf16* __restrict__ kg,
                                                const bf16* __restrict__ vg,
                                                bf16* __restrict__ og) {
  __shared__ __align__(16) bf16 Ks[64][72];
  __shared__ __align__(16) bf16 Vt[64][72];
  __shared__ __align__(16) bf16 Pl[4][32][72];

  const int tid = threadIdx.x;
  const int l = tid & 63, w = tid >> 6;
  const int lr = l & 15, lg = l >> 4;
  const int bh = blockIdx.y;
  const int q0 = blockIdx.x * 128;
  const size_t hb = (size_t)bh * SDIM * HDIM;
  const bf16* Q  = qg + hb;
  const bf16* Kp = kg + hb;
  const bf16* Vp = vg + hb;

  // Q fragments in registers
  bf16x8 qf[2][2];
#pragma unroll
  for (int rf = 0; rf < 2; ++rf)
#pragma unroll
    for (int c = 0; c < 2; ++c)
      qf[rf][c] = *(const bf16x8*)(Q + (size_t)(q0 + 32 * w + 16 * rf + lr) * HDIM + c * 32 + lg * 8);

  f32x4 o[2][4] = {};
  float mrow[2][4], lrow[2][4];
#pragma unroll
  for (int rf = 0; rf < 2; ++rf)
#pragma unroll
    for (int r = 0; r < 4; ++r) { mrow[rf][r] = -1e30f; lrow[rf][r] = 0.f; }

  const int ntiles = (q0 + 128) / 64;
  const int ntw = (q0 + 32 * w + 95) / 64;  // tiles this wave actually needs

  for (int t = 0; t < ntiles; ++t) {
    const int k0 = t * 64;
    __syncthreads();
    // stage K tile [64][64] -> Ks
    {
      int row = tid >> 2, cg = (tid & 3) << 4;
      const bf16* src = Kp + (size_t)(k0 + row) * HDIM + cg;
      bf16x8 v0 = *(const bf16x8*)(src);
      bf16x8 v1 = *(const bf16x8*)(src + 8);
      *(bf16x8*)&Ks[row][cg] = v0;
      *(bf16x8*)&Ks[row][cg + 8] = v1;
    }
    // stage V tile transposed -> Vt[d][key]
#pragma unroll
    for (int i = 0; i < 2; ++i) {
      int lin = (i * 256 + tid) * 8;
      int key = lin >> 6, d0 = lin & 63;
      bf16x8 v = *(const bf16x8*)(Vp + (size_t)(k0 + key) * HDIM + d0);
#pragma unroll
      for (int j = 0; j < 8; ++j) Vt[d0 + j][key] = v[j];
    }
    __syncthreads();

    if (t < ntw) {
      // QK^T
      f32x4 sc[2][4] = {};
#pragma unroll
      for (int c = 0; c < 2; ++c) {
        bf16x8 kf[4];
#pragma unroll
        for (int f = 0; f < 4; ++f)
          kf[f] = *(const bf16x8*)(&Ks[f * 16 + lr][c * 32 + lg * 8]);
#pragma unroll
        for (int rf = 0; rf < 2; ++rf)
#pragma unroll
          for (int f = 0; f < 4; ++f)
            sc[rf][f] = MFMA16(qf[rf][c], kf[f], sc[rf][f]);
      }
      // online softmax
#pragma unroll
      for (int rf = 0; rf < 2; ++rf) {
        float mx[4];
#pragma unroll
        for (int r = 0; r < 4; ++r) mx[r] = -1e30f;
#pragma unroll
        for (int f = 0; f < 4; ++f)
#pragma unroll
          for (int r = 0; r < 4; ++r) {
            float s = sc[rf][f][r] * 0.125f;
            int key = k0 + f * 16 + lr;
            int qr  = q0 + 32 * w + 16 * rf + lg * 4 + r;
            s = (key <= qr) ? s : -1e30f;
            sc[rf][f][r] = s;
            mx[r] = fmaxf(mx[r], s);
          }
#pragma unroll
        for (int off = 1; off < 16; off <<= 1)
#pragma unroll
          for (int r = 0; r < 4; ++r) mx[r] = fmaxf(mx[r], __shfl_xor(mx[r], off));
        float rs[4];
#pragma unroll
        for (int r = 0; r < 4; ++r) {
          float mnew = fmaxf(mrow[rf][r], mx[r]);
          float corr = __expf(mrow[rf][r] - mnew);
          mrow[rf][r] = mnew;
          lrow[rf][r] *= corr;
#pragma unroll
          for (int n = 0; n < 4; ++n) o[rf][n][r] *= corr;
          rs[r] = 0.f;
        }
#pragma unroll
        for (int f = 0; f < 4; ++f)
#pragma unroll
          for (int r = 0; r < 4; ++r) {
            float p = __expf(sc[rf][f][r] - mrow[rf][r]);
            rs[r] += p;
            Pl[w][rf * 16 + lg * 4 + r][f * 16 + lr] = (__bf16)p;
          }
#pragma unroll
        for (int off = 1; off < 16; off <<= 1)
#pragma unroll
          for (int r = 0; r < 4; ++r) rs[r] += __shfl_xor(rs[r], off);
#pragma unroll
        for (int r = 0; r < 4; ++r) lrow[rf][r] += rs[r];
      }
      // PV
#pragma unroll
      for (int c = 0; c < 2; ++c) {
        bf16x8 vf[4];
#pragma unroll
        for (int n = 0; n < 4; ++n)
          vf[n] = *(const bf16x8*)(&Vt[n * 16 + lr][c * 32 + lg * 8]);
#pragma unroll
        for (int rf = 0; rf < 2; ++rf) {
          bf16x8 pf = *(const bf16x8*)(&Pl[w][rf * 16 + lr][c * 32 + lg * 8]);
#pragma unroll
          for (int n = 0; n < 4; ++n) o[rf][n] = MFMA16(pf, vf[n], o[rf][n]);
        }
      }
    }
  }

  // epilogue: O/l -> [B][S][D] bf16
  const int b = bh >> 4, h = bh & 15;
#pragma unroll
  for (int rf = 0; rf < 2; ++rf)
#pragma unroll
    for (int n = 0; n < 4; ++n)
#pragma unroll
      for (int r = 0; r < 4; ++r) {
        int qr = q0 + 32 * w + 16 * rf + lg * 4 + r;
        int col = h * HDIM + n * 16 + lr;
        float v = o[rf][n][r] / lrow[rf][r];
        og[((size_t)(b * SDIM + qr)) * DDIM + col] = (__bf16)v;
      }
}

// ---------------------------------------------------------------- launch
extern "C" void kernel_launch(void* const* d_in, const int* in_sizes, int n_in,
                              void* d_out, int out_size, void* d_ws, size_t ws_size,
                              hipStream_t stream) {
  const float* x  = (const float*)d_in[0];
  const float* wq = (const float*)d_in[1];
  const float* wk = (const float*)d_in[2];
  const float* wv = (const float*)d_in[3];
  const float* wo = (const float*)d_in[4];

  char* ws = (char*)d_ws;
  const size_t MB = 1024 * 1024;
  bf16* xb   = (bf16*)(ws + 0);        // 8 MB
  bf16* wqb  = (bf16*)(ws + 8 * MB);   // 2 MB (wq,wk,wv contiguous for grid.z)
  bf16* wkb  = (bf16*)(ws + 10 * MB);
  bf16* wvb  = (bf16*)(ws + 12 * MB);
  bf16* wob  = (bf16*)(ws + 14 * MB);
  bf16* qb   = (bf16*)(ws + 16 * MB);  // 8 MB each, q,k,v contiguous
  bf16* kb   = (bf16*)(ws + 24 * MB);
  bf16* vb   = (bf16*)(ws + 32 * MB);
  bf16* ob   = (bf16*)(ws + 40 * MB);  // 8 MB
  float* cosT = (float*)(ws + 48 * MB);
  float* sinT = (float*)(ws + 49 * MB);
  (void)wkb; (void)wvb;

  const int NX = BDIM * SDIM * DDIM;  // 4194304
  const int NW = DDIM * DDIM;         // 1048576

  cvt_bf16<<<NX / 4 / 256, 256, 0, stream>>>(x, xb, NX / 4);
  cvt_bf16<<<NW / 4 / 256, 256, 0, stream>>>(wq, wqb, NW / 4);
  cvt_bf16<<<NW / 4 / 256, 256, 0, stream>>>(wk, wkb, NW / 4);
  cvt_bf16<<<NW / 4 / 256, 256, 0, stream>>>(wv, wvb, NW / 4);
  cvt_bf16<<<NW / 4 / 256, 256, 0, stream>>>(wo, wob, NW / 4);
  rope_table<<<(SDIM * 32) / 256, 256, 0, stream>>>(cosT, sinT);
  gemm_bt<0><<<dim3(8, 32, 3), 256, 0, stream>>>(xb, wqb, (void*)qb);
  rope_apply<<<(32 * SDIM * 32) / 256, 256, 0, stream>>>(qb, kb, cosT, sinT);
  attn_fwd<<<dim3(16, 32), 256, 0, stream>>>(qb, kb, vb, ob);
  gemm_bt<1><<<dim3(8, 32, 1), 256, 0, stream>>>(ob, wob, d_out);
}

// Round 2
// 205.142 us; speedup vs baseline: 1.2641x; 1.2641x over previous
//
#include <hip/hip_runtime.h>
#include <hip/hip_bf16.h>
#include <cstdint>
#include <cstddef>

// Problem constants
#define BDIM 2
#define SDIM 2048
#define DDIM 1024
#define HN   16
#define HDIM 64

using bf16 = __bf16;
typedef __attribute__((ext_vector_type(8))) __bf16 bf16x8;
typedef __attribute__((ext_vector_type(8))) unsigned short ushort8;
typedef __attribute__((ext_vector_type(4))) float  f32x4;

#define MFMA16(a, b, c) __builtin_amdgcn_mfma_f32_16x16x32_bf16((a), (b), (c), 0, 0, 0)

#define ASYNC16(g, l)                                                          \
  __builtin_amdgcn_global_load_lds(                                            \
      (const __attribute__((address_space(1))) void*)(g),                      \
      (__attribute__((address_space(3))) void*)(l), 16, 0, 0)

// scale folded into Q at rope time: 1/sqrt(64) * log2(e)  (softmax in exp2 domain)
#define QSCALE 0.1803368801111204f

// ---------------------------------------------------------------- conversions
__global__ __launch_bounds__(256) void cvt_bf16(const float* __restrict__ src,
                                                bf16* __restrict__ dst, int n4) {
  int i = blockIdx.x * 256 + threadIdx.x;
  if (i < n4) {
    float4 v = ((const float4*)src)[i];
    typedef __attribute__((ext_vector_type(4))) __bf16 bf16x4;
    bf16x4 o = {(__bf16)v.x, (__bf16)v.y, (__bf16)v.z, (__bf16)v.w};
    *(bf16x4*)(dst + (size_t)i * 4) = o;
  }
}

// ---------------------------------------------------------------- rope table
__global__ __launch_bounds__(256) void rope_table(float* __restrict__ cosT,
                                                  float* __restrict__ sinT) {
  int i = blockIdx.x * 256 + threadIdx.x;  // SDIM*32 threads
  int s = i >> 5, j = i & 31;
  float inv = powf(10000.f, -(float)j * (1.f / 32.f));
  float a = (float)s * inv;
  float sn, c;
  sincosf(a, &sn, &c);
  cosT[s * 64 + j]      = c;
  cosT[s * 64 + j + 32] = c;
  sinT[s * 64 + j]      = sn;
  sinT[s * 64 + j + 32] = sn;
}

// ---------------------------------------------------------------- rope apply (in-place; q also pre-scaled)
__global__ __launch_bounds__(256) void rope_apply(bf16* __restrict__ q,
                                                  bf16* __restrict__ k,
                                                  const float* __restrict__ cosT,
                                                  const float* __restrict__ sinT) {
  int i = blockIdx.x * 256 + threadIdx.x;  // 32*SDIM*32 threads
  int j = i & 31;
  int s = (i >> 5) & (SDIM - 1);
  int bh = i >> 16;  // SDIM*32 == 1<<16
  size_t base = ((size_t)bh * SDIM + s) * HDIM;
  float c = cosT[s * 64 + j], sn = sinT[s * 64 + j];
  float a = (float)q[base + j], b2 = (float)q[base + j + 32];
  q[base + j]      = (__bf16)((a * c - b2 * sn) * QSCALE);
  q[base + j + 32] = (__bf16)((b2 * c + a * sn) * QSCALE);
  a = (float)k[base + j]; b2 = (float)k[base + j + 32];
  k[base + j]      = (__bf16)(a * c - b2 * sn);
  k[base + j + 32] = (__bf16)(b2 * c + a * sn);
}

// ---------------------------------------------------------------- V transpose: [bh][s][64] -> [bh][64][s]
__global__ __launch_bounds__(256) void transpose_v(const unsigned short* __restrict__ v,
                                                   unsigned short* __restrict__ vt) {
  const int bh = blockIdx.y;
  const int s_base = blockIdx.x * 32 + (threadIdx.x >> 6) * 8;
  const int d = threadIdx.x & 63;
  const unsigned short* src = v + ((size_t)bh * SDIM + s_base) * HDIM + d;
  ushort8 o;
#pragma unroll
  for (int j = 0; j < 8; ++j) o[j] = src[(size_t)j * HDIM];  // coalesced: 64 lanes x 2B = 128B/line
  *(ushort8*)(vt + ((size_t)bh * HDIM + d) * SDIM + s_base) = o;
}

// ---------------------------------------------------------------- GEMM  C = A * B^T
// A: [4096][1024] bf16 row-major, Bw: [1024][1024] bf16 row-major (rows = out features)
// MODE 0: write bf16 to [B][H][S][HD] (QKV), blockIdx.z selects weight/output
// MODE 1: write fp32 row-major [4096][1024]
template <int MODE>
__global__ __launch_bounds__(256) void gemm_bt(const bf16* __restrict__ A,
                                               const bf16* __restrict__ B0,
                                               void* __restrict__ C0) {
  constexpr int K = 1024;
  __shared__ __align__(16) bf16 As[128 * 64];
  __shared__ __align__(16) bf16 Bs[128 * 64];
  const int tid = threadIdx.x;
  const int l = tid & 63, w = tid >> 6;
  const int wr = w >> 1, wc = w & 1;
  const int lr = l & 15, lg = l >> 4;
  const int bm = blockIdx.y * 128;
  const int bn = blockIdx.x * 128;
  const bf16* Bw = B0 + (size_t)blockIdx.z * (1024 * 1024);

  f32x4 acc[4][4] = {};

  for (int k0 = 0; k0 < K; k0 += 64) {
    __syncthreads();
#pragma unroll
    for (int i = 0; i < 4; ++i) {
      int idx = i * 2048 + tid * 8;
      int row = idx >> 6, col = idx & 63;
      ASYNC16(A + (size_t)(bm + row) * K + (k0 + col), As + idx);
      ASYNC16(Bw + (size_t)(bn + row) * K + (k0 + col), Bs + idx);
    }
    __syncthreads();
#pragma unroll
    for (int c = 0; c < 2; ++c) {
      bf16x8 af[4], bfr[4];
#pragma unroll
      for (int m = 0; m < 4; ++m)
        af[m] = *(const bf16x8*)(As + (wr * 64 + m * 16 + lr) * 64 + c * 32 + lg * 8);
#pragma unroll
      for (int n = 0; n < 4; ++n)
        bfr[n] = *(const bf16x8*)(Bs + (wc * 64 + n * 16 + lr) * 64 + c * 32 + lg * 8);
#pragma unroll
      for (int m = 0; m < 4; ++m)
#pragma unroll
        for (int n = 0; n < 4; ++n)
          acc[m][n] = MFMA16(af[m], bfr[n], acc[m][n]);
    }
  }

#pragma unroll
  for (int m = 0; m < 4; ++m) {
#pragma unroll
    for (int n = 0; n < 4; ++n) {
#pragma unroll
      for (int r = 0; r < 4; ++r) {
        int row = bm + wr * 64 + m * 16 + lg * 4 + r;
        int col = bn + wc * 64 + n * 16 + lr;
        float v = acc[m][n][r];
        if constexpr (MODE == 0) {
          bf16* C = (bf16*)C0 + (size_t)blockIdx.z * ((size_t)BDIM * SDIM * DDIM);
          size_t off = (((size_t)(row >> 11) * HN + (col >> 6)) * SDIM + (row & (SDIM - 1))) * HDIM + (col & 63);
          C[off] = (__bf16)v;
        } else {
          ((float*)C0)[(size_t)row * DDIM + col] = v;
        }
      }
    }
  }
}

// ---------------------------------------------------------------- flash attention (causal, balanced)
// Q/K: [B*H][S][HD] bf16 (roped, Q pre-scaled). Vt: [B*H][HD][S] bf16.
// Output: [B][S][D] bf16 row-major.
// Block = 4 waves, processes q-tile pair (p, 31-p): exactly 33 KV stages each.
// K/V staged chunk-linear in LDS via per-lane-source global_load_lds:
//   chunk m = c*4+f holds frag rows f*16+lr, cols c*32+lg*8 at [m*512 + lane*8].
__global__ __launch_bounds__(256) void attn_fwd(const bf16* __restrict__ qg,
                                                const bf16* __restrict__ kg,
                                                const bf16* __restrict__ vtg,
                                                bf16* __restrict__ og) {
  __shared__ __align__(16) bf16 Ks[8 * 512];
  __shared__ __align__(16) bf16 Vs[8 * 512];
  __shared__ __align__(16) bf16 Pl[4][16 * 72];

  const int tid = threadIdx.x;
  const int l = tid & 63, w = tid >> 6;
  const int lr = l & 15, lg = l >> 4;
  const int bh = blockIdx.y;
  const size_t hb = (size_t)bh * SDIM * HDIM;
  const bf16* Q  = qg + hb;
  const bf16* Kp = kg + hb;
  const bf16* Vp = vtg + hb;  // [64][SDIM]
  const int b = bh >> 4, h = bh & 15;

  for (int phase = 0; phase < 2; ++phase) {
    const int qt = phase ? (31 - blockIdx.x) : blockIdx.x;
    const int q0 = qt * 64;

    bf16x8 qf[2];
#pragma unroll
    for (int c = 0; c < 2; ++c)
      qf[c] = *(const bf16x8*)(Q + (size_t)(q0 + w * 16 + lr) * HDIM + c * 32 + lg * 8);

    f32x4 o[4] = {};
    float m[4], lsum[4];
#pragma unroll
    for (int r = 0; r < 4; ++r) { m[r] = -3e38f; lsum[r] = 0.f; }

    for (int t = 0; t <= qt; ++t) {
      const int k0 = t * 64;
      __syncthreads();  // previous tile's LDS fully consumed
#pragma unroll
      for (int u = 0; u < 2; ++u) {
        const int mm = 2 * w + u;
        const int f = mm & 3, c = mm >> 2;
        ASYNC16(Kp + (size_t)(k0 + f * 16 + lr) * HDIM + c * 32 + lg * 8,
                Ks + mm * 512 + l * 8);
        ASYNC16(Vp + (size_t)(f * 16 + lr) * SDIM + k0 + c * 32 + lg * 8,
                Vs + mm * 512 + l * 8);
      }
      __syncthreads();  // staging visible

      const bool diag = (t == qt);
      const int fLim = diag ? w : 3;

      // QK^T (skip fully-masked frags on diagonal tile)
      f32x4 sc[4] = {};
#pragma unroll
      for (int c = 0; c < 2; ++c)
#pragma unroll
        for (int f = 0; f < 4; ++f)
          if (f <= fLim) {
            bf16x8 kfr = *(const bf16x8*)(Ks + (c * 4 + f) * 512 + l * 8);
            sc[f] = MFMA16(qf[c], kfr, sc[f]);
          }

      // mask + row max (rows r: q = q0+16w+lg*4+r; cols: key = k0+f*16+lr)
      float mx[4] = {-3e38f, -3e38f, -3e38f, -3e38f};
#pragma unroll
      for (int f = 0; f < 4; ++f)
#pragma unroll
        for (int r = 0; r < 4; ++r) {
          float s = sc[f][r];
          bool valid = !diag || (f < w) || (f == w && lr <= lg * 4 + r);
          s = valid ? s : -3e38f;
          sc[f][r] = s;
          mx[r] = fmaxf(mx[r], s);
        }
#pragma unroll
      for (int off = 1; off < 16; off <<= 1)
#pragma unroll
        for (int r = 0; r < 4; ++r) mx[r] = fmaxf(mx[r], __shfl_xor(mx[r], off));

      float rs[4];
#pragma unroll
      for (int r = 0; r < 4; ++r) {
        float mnew = fmaxf(m[r], mx[r]);
        float corr = exp2f(m[r] - mnew);
        m[r] = mnew;
        lsum[r] *= corr;
#pragma unroll
        for (int n = 0; n < 4; ++n) o[n][r] *= corr;
        rs[r] = 0.f;
      }
#pragma unroll
      for (int f = 0; f < 4; ++f)
#pragma unroll
        for (int r = 0; r < 4; ++r) {
          float p = exp2f(sc[f][r] - m[r]);
          rs[r] += p;
          Pl[w][(lg * 4 + r) * 72 + f * 16 + lr] = (__bf16)p;
        }
#pragma unroll
      for (int off = 1; off < 16; off <<= 1)
#pragma unroll
        for (int r = 0; r < 4; ++r) rs[r] += __shfl_xor(rs[r], off);
#pragma unroll
      for (int r = 0; r < 4; ++r) lsum[r] += rs[r];

      // PV
#pragma unroll
      for (int c = 0; c < 2; ++c) {
        bf16x8 pf = *(const bf16x8*)(Pl[w] + lr * 72 + c * 32 + lg * 8);
#pragma unroll
        for (int n = 0; n < 4; ++n) {
          bf16x8 vfr = *(const bf16x8*)(Vs + (c * 4 + n) * 512 + l * 8);
          o[n] = MFMA16(pf, vfr, o[n]);
        }
      }
    }

    // epilogue for this phase
#pragma unroll
    for (int r = 0; r < 4; ++r) {
      float rl = 1.f / lsum[r];
      int qr = q0 + 16 * w + lg * 4 + r;
#pragma unroll
      for (int n = 0; n < 4; ++n)
        og[((size_t)(b * SDIM + qr)) * DDIM + h * HDIM + n * 16 + lr] =
            (__bf16)(o[n][r] * rl);
    }
  }
}

// ---------------------------------------------------------------- launch
extern "C" void kernel_launch(void* const* d_in, const int* in_sizes, int n_in,
                              void* d_out, int out_size, void* d_ws, size_t ws_size,
                              hipStream_t stream) {
  const float* x  = (const float*)d_in[0];
  const float* wq = (const float*)d_in[1];
  const float* wk = (const float*)d_in[2];
  const float* wv = (const float*)d_in[3];
  const float* wo = (const float*)d_in[4];

  char* ws = (char*)d_ws;
  const size_t MB = 1024 * 1024;
  bf16* xb   = (bf16*)(ws + 0);        // 8 MB (reused as vtb after QKV GEMM)
  bf16* wqb  = (bf16*)(ws + 8 * MB);   // wq,wk,wv contiguous for grid.z
  bf16* wkb  = (bf16*)(ws + 10 * MB);
  bf16* wvb  = (bf16*)(ws + 12 * MB);
  bf16* wob  = (bf16*)(ws + 14 * MB);
  bf16* qb   = (bf16*)(ws + 16 * MB);  // 8 MB each
  bf16* kb   = (bf16*)(ws + 24 * MB);
  bf16* vb   = (bf16*)(ws + 32 * MB);
  bf16* ob   = (bf16*)(ws + 40 * MB);  // 8 MB
  float* cosT = (float*)(ws + 48 * MB);
  float* sinT = (float*)(ws + 49 * MB);
  bf16* vtb  = xb;  // V transposed [bh][64][S], overwrites xb (free after QKV GEMM)
  (void)wkb; (void)wvb;

  const int NX = BDIM * SDIM * DDIM;  // 4194304
  const int NW = DDIM * DDIM;         // 1048576

  cvt_bf16<<<NX / 4 / 256, 256, 0, stream>>>(x, xb, NX / 4);
  cvt_bf16<<<NW / 4 / 256, 256, 0, stream>>>(wq, wqb, NW / 4);
  cvt_bf16<<<NW / 4 / 256, 256, 0, stream>>>(wk, wkb, NW / 4);
  cvt_bf16<<<NW / 4 / 256, 256, 0, stream>>>(wv, wvb, NW / 4);
  cvt_bf16<<<NW / 4 / 256, 256, 0, stream>>>(wo, wob, NW / 4);
  rope_table<<<(SDIM * 32) / 256, 256, 0, stream>>>(cosT, sinT);
  gemm_bt<0><<<dim3(8, 32, 3), 256, 0, stream>>>(xb, wqb, (void*)qb);
  rope_apply<<<(32 * SDIM * 32) / 256, 256, 0, stream>>>(qb, kb, cosT, sinT);
  transpose_v<<<dim3(SDIM / 32, 32), 256, 0, stream>>>((const unsigned short*)vb,
                                                       (unsigned short*)vtb);
  attn_fwd<<<dim3(16, 32), 256, 0, stream>>>(qb, kb, vtb, ob);
  gemm_bt<1><<<dim3(8, 32, 1), 256, 0, stream>>>(ob, wob, d_out);
}

// Round 3
// 173.521 us; speedup vs baseline: 1.4944x; 1.1822x over previous
//
#include <hip/hip_runtime.h>
#include <hip/hip_bf16.h>
#include <cstdint>
#include <cstddef>

// Problem constants
#define BDIM 2
#define SDIM 2048
#define DDIM 1024
#define HN   16
#define HDIM 64

using bf16 = __bf16;
typedef __attribute__((ext_vector_type(8))) __bf16 bf16x8;
typedef __attribute__((ext_vector_type(4))) __bf16 bf16x4;
typedef __attribute__((ext_vector_type(8))) unsigned short ushort8;
typedef __attribute__((ext_vector_type(4))) float  f32x4;

#define MFMA16(a, b, c) __builtin_amdgcn_mfma_f32_16x16x32_bf16((a), (b), (c), 0, 0, 0)

#define ASYNC16(g, l)                                                          \
  __builtin_amdgcn_global_load_lds(                                            \
      (const __attribute__((address_space(1))) void*)(g),                      \
      (__attribute__((address_space(3))) void*)(l), 16, 0, 0)

// scale folded into Q at rope time: 1/sqrt(64) * log2(e)  (softmax in exp2 domain)
#define QSCALE 0.1803368801111204f

// ---------------------------------------------------------------- conversions
__global__ __launch_bounds__(256) void cvt_bf16(const float* __restrict__ src,
                                                bf16* __restrict__ dst, int n4) {
  int i = blockIdx.x * 256 + threadIdx.x;
  if (i < n4) {
    float4 v = ((const float4*)src)[i];
    bf16x4 o = {(__bf16)v.x, (__bf16)v.y, (__bf16)v.z, (__bf16)v.w};
    *(bf16x4*)(dst + (size_t)i * 4) = o;
  }
}

// ---------------------------------------------------------------- rope table
__global__ __launch_bounds__(256) void rope_table(float* __restrict__ cosT,
                                                  float* __restrict__ sinT) {
  int i = blockIdx.x * 256 + threadIdx.x;  // SDIM*32 threads
  int s = i >> 5, j = i & 31;
  float inv = powf(10000.f, -(float)j * (1.f / 32.f));
  float a = (float)s * inv;
  float sn, c;
  sincosf(a, &sn, &c);
  cosT[s * 64 + j]      = c;
  cosT[s * 64 + j + 32] = c;
  sinT[s * 64 + j]      = sn;
  sinT[s * 64 + j + 32] = sn;
}

// ---------------------------------------------------------------- rope apply (in-place; q also pre-scaled)
__global__ __launch_bounds__(256) void rope_apply(bf16* __restrict__ q,
                                                  bf16* __restrict__ k,
                                                  const float* __restrict__ cosT,
                                                  const float* __restrict__ sinT) {
  int i = blockIdx.x * 256 + threadIdx.x;  // 32*SDIM*32 threads
  int j = i & 31;
  int s = (i >> 5) & (SDIM - 1);
  int bh = i >> 16;  // SDIM*32 == 1<<16
  size_t base = ((size_t)bh * SDIM + s) * HDIM;
  float c = cosT[s * 64 + j], sn = sinT[s * 64 + j];
  float a = (float)q[base + j], b2 = (float)q[base + j + 32];
  q[base + j]      = (__bf16)((a * c - b2 * sn) * QSCALE);
  q[base + j + 32] = (__bf16)((b2 * c + a * sn) * QSCALE);
  a = (float)k[base + j]; b2 = (float)k[base + j + 32];
  k[base + j]      = (__bf16)(a * c - b2 * sn);
  k[base + j + 32] = (__bf16)(b2 * c + a * sn);
}

// ---------------------------------------------------------------- V transpose: [bh][s][64] -> [bh][64][s]
__global__ __launch_bounds__(256) void transpose_v(const unsigned short* __restrict__ v,
                                                   unsigned short* __restrict__ vt) {
  const int bh = blockIdx.y;
  const int s_base = blockIdx.x * 32 + (threadIdx.x >> 6) * 8;
  const int d = threadIdx.x & 63;
  const unsigned short* src = v + ((size_t)bh * SDIM + s_base) * HDIM + d;
  ushort8 o;
#pragma unroll
  for (int j = 0; j < 8; ++j) o[j] = src[(size_t)j * HDIM];  // coalesced: 64 lanes x 2B = 128B/line
  *(ushort8*)(vt + ((size_t)bh * HDIM + d) * SDIM + s_base) = o;
}

// ---------------------------------------------------------------- GEMM  C = A * B^T
// A: [4096][1024] bf16 row-major, Bw: [1024][1024] bf16 row-major (rows = out features)
// MODE 0: write bf16 to [B][H][S][HD] (QKV), blockIdx.z selects weight/output
// MODE 1: write fp32 row-major [4096][1024]
template <int MODE>
__global__ __launch_bounds__(256) void gemm_bt(const bf16* __restrict__ A,
                                               const bf16* __restrict__ B0,
                                               void* __restrict__ C0) {
  constexpr int K = 1024;
  __shared__ __align__(16) bf16 As[128 * 64];
  __shared__ __align__(16) bf16 Bs[128 * 64];
  const int tid = threadIdx.x;
  const int l = tid & 63, w = tid >> 6;
  const int wr = w >> 1, wc = w & 1;
  const int lr = l & 15, lg = l >> 4;
  const int bm = blockIdx.y * 128;
  const int bn = blockIdx.x * 128;
  const bf16* Bw = B0 + (size_t)blockIdx.z * (1024 * 1024);

  f32x4 acc[4][4] = {};

  for (int k0 = 0; k0 < K; k0 += 64) {
    __syncthreads();
#pragma unroll
    for (int i = 0; i < 4; ++i) {
      int idx = i * 2048 + tid * 8;
      int row = idx >> 6, col = idx & 63;
      ASYNC16(A + (size_t)(bm + row) * K + (k0 + col), As + idx);
      ASYNC16(Bw + (size_t)(bn + row) * K + (k0 + col), Bs + idx);
    }
    __syncthreads();
#pragma unroll
    for (int c = 0; c < 2; ++c) {
      bf16x8 af[4], bfr[4];
#pragma unroll
      for (int m = 0; m < 4; ++m)
        af[m] = *(const bf16x8*)(As + (wr * 64 + m * 16 + lr) * 64 + c * 32 + lg * 8);
#pragma unroll
      for (int n = 0; n < 4; ++n)
        bfr[n] = *(const bf16x8*)(Bs + (wc * 64 + n * 16 + lr) * 64 + c * 32 + lg * 8);
#pragma unroll
      for (int m = 0; m < 4; ++m)
#pragma unroll
        for (int n = 0; n < 4; ++n)
          acc[m][n] = MFMA16(af[m], bfr[n], acc[m][n]);
    }
  }

#pragma unroll
  for (int m = 0; m < 4; ++m) {
#pragma unroll
    for (int n = 0; n < 4; ++n) {
#pragma unroll
      for (int r = 0; r < 4; ++r) {
        int row = bm + wr * 64 + m * 16 + lg * 4 + r;
        int col = bn + wc * 64 + n * 16 + lr;
        float v = acc[m][n][r];
        if constexpr (MODE == 0) {
          bf16* C = (bf16*)C0 + (size_t)blockIdx.z * ((size_t)BDIM * SDIM * DDIM);
          size_t off = (((size_t)(row >> 11) * HN + (col >> 6)) * SDIM + (row & (SDIM - 1))) * HDIM + (col & 63);
          C[off] = (__bf16)v;
        } else {
          ((float*)C0)[(size_t)row * DDIM + col] = v;
        }
      }
    }
  }
}

// ---------------------------------------------------------------- flash attention (causal, balanced, swapped-QK^T)
// Q/K: [B*H][S][HD] bf16 (roped, Q pre-scaled by 1/8*log2e). Vt: [B*H][HD][S].
// Block = 4 waves, q-tile pair (p, 31-p): exactly 33 KV stages. Double-buffered
// K/V staging (1 barrier per tile). QK^T computed swapped (K as A operand) so
// each lane owns one q-row's scores: in-register softmax, scalar m/lsum.
__global__ __launch_bounds__(256) void attn_fwd(const bf16* __restrict__ qg,
                                                const bf16* __restrict__ kg,
                                                const bf16* __restrict__ vtg,
                                                bf16* __restrict__ og) {
  __shared__ __align__(16) bf16 Ks[2][8 * 512];
  __shared__ __align__(16) bf16 Vs[2][8 * 512];
  __shared__ __align__(16) bf16 Pl[4][16 * 72];

  const int tid = threadIdx.x;
  const int l = tid & 63, w = tid >> 6;
  const int lr = l & 15, lg = l >> 4;
  const int bh = blockIdx.y;
  const size_t hb = (size_t)bh * SDIM * HDIM;
  const bf16* Q  = qg + hb;
  const bf16* Kp = kg + hb;
  const bf16* Vp = vtg + hb;  // [64][SDIM]
  const int b = bh >> 4, h = bh & 15;
  bf16* Pw = &Pl[w][0];

  for (int phase = 0; phase < 2; ++phase) {
    const int qt = phase ? (31 - blockIdx.x) : blockIdx.x;
    const int q0 = qt * 64;

    bf16x8 qf[2];
#pragma unroll
    for (int c = 0; c < 2; ++c)
      qf[c] = *(const bf16x8*)(Q + (size_t)(q0 + w * 16 + lr) * HDIM + c * 32 + lg * 8);

    f32x4 o[4] = {};
    float m = -3e38f, lsum = 0.f;

    // prologue: stage tile 0 into buffer 0
#pragma unroll
    for (int u = 0; u < 2; ++u) {
      const int mm = 2 * w + u, f = mm & 3, c = mm >> 2;
      ASYNC16(Kp + (size_t)(f * 16 + lr) * HDIM + c * 32 + lg * 8,
              Ks[0] + mm * 512 + l * 8);
      ASYNC16(Vp + (size_t)(f * 16 + lr) * SDIM + c * 32 + lg * 8,
              Vs[0] + mm * 512 + l * 8);
    }
    __syncthreads();

    for (int t = 0; t <= qt; ++t) {
      const int cur = t & 1;
      // issue next tile's staging into the other buffer (hidden under compute)
      if (t < qt) {
        const int k1 = (t + 1) * 64;
#pragma unroll
        for (int u = 0; u < 2; ++u) {
          const int mm = 2 * w + u, f = mm & 3, c = mm >> 2;
          ASYNC16(Kp + (size_t)(k1 + f * 16 + lr) * HDIM + c * 32 + lg * 8,
                  Ks[cur ^ 1] + mm * 512 + l * 8);
          ASYNC16(Vp + (size_t)(f * 16 + lr) * SDIM + k1 + c * 32 + lg * 8,
                  Vs[cur ^ 1] + mm * 512 + l * 8);
        }
      }

      const bool diag = (t == qt);
      const int fLim = diag ? w : 3;

      // swapped QK^T: sc[f] col=q-row(lr), row=key(f*16+lg*4+r)
      f32x4 sc[4] = {};
#pragma unroll
      for (int c = 0; c < 2; ++c)
#pragma unroll
        for (int f = 0; f < 4; ++f)
          if (f <= fLim) {
            bf16x8 kfr = *(const bf16x8*)(Ks[cur] + (c * 4 + f) * 512 + l * 8);
            sc[f] = MFMA16(kfr, qf[c], sc[f]);
          }

      if (diag) {
#pragma unroll
        for (int f = 0; f < 4; ++f)
#pragma unroll
          for (int r = 0; r < 4; ++r) {
            if (f > w)
              sc[f][r] = -3e38f;
            else if (f == w)
              sc[f][r] = (lg * 4 + r <= lr) ? sc[f][r] : -3e38f;
          }
      }

      // row max: 16 in-register + 2 cross-lane
      float mx = -3e38f;
#pragma unroll
      for (int f = 0; f < 4; ++f)
#pragma unroll
        for (int r = 0; r < 4; ++r) mx = fmaxf(mx, sc[f][r]);
      mx = fmaxf(mx, __shfl_xor(mx, 16));
      mx = fmaxf(mx, __shfl_xor(mx, 32));

      // defer-max: rescale only when the running max grew materially
      if (!__all(mx - m <= 8.f)) {
        float mnew = fmaxf(m, mx);
        float corr = exp2f(m - mnew);
        m = mnew;
        lsum *= corr;
        float cb[4];
#pragma unroll
        for (int r = 0; r < 4; ++r) cb[r] = __shfl(corr, lg * 4 + r);
#pragma unroll
        for (int n = 0; n < 4; ++n)
#pragma unroll
          for (int r = 0; r < 4; ++r) o[n][r] *= cb[r];
      }

      // P = exp2(sc - m); packed b64 stores to Pl[q][key]
      float rs = 0.f;
#pragma unroll
      for (int f = 0; f < 4; ++f) {
        float p0 = exp2f(sc[f][0] - m);
        float p1 = exp2f(sc[f][1] - m);
        float p2 = exp2f(sc[f][2] - m);
        float p3 = exp2f(sc[f][3] - m);
        rs += (p0 + p1) + (p2 + p3);
        bf16x4 pv = {(__bf16)p0, (__bf16)p1, (__bf16)p2, (__bf16)p3};
        *(bf16x4*)(Pw + lr * 72 + f * 16 + lg * 4) = pv;
      }
      rs += __shfl_xor(rs, 16);
      rs += __shfl_xor(rs, 32);
      lsum += rs;

      // PV (skip fully-zero key chunks on the diagonal tile)
      const int cLim = diag ? (w >> 1) : 1;
#pragma unroll
      for (int c = 0; c < 2; ++c)
        if (c <= cLim) {
          bf16x8 pf = *(const bf16x8*)(Pw + lr * 72 + c * 32 + lg * 8);
#pragma unroll
          for (int n = 0; n < 4; ++n) {
            bf16x8 vfr = *(const bf16x8*)(Vs[cur] + (c * 4 + n) * 512 + l * 8);
            o[n] = MFMA16(pf, vfr, o[n]);
          }
        }

      __syncthreads();  // buf[cur] consumed by all; buf[cur^1] staged+visible
    }

    // epilogue: broadcast lsum from softmax layout (per lr) to O layout (per lg*4+r)
    float lb[4];
#pragma unroll
    for (int r = 0; r < 4; ++r) lb[r] = __shfl(lsum, lg * 4 + r);
#pragma unroll
    for (int r = 0; r < 4; ++r) {
      float rl = 1.f / lb[r];
      int qr = q0 + 16 * w + lg * 4 + r;
#pragma unroll
      for (int n = 0; n < 4; ++n)
        og[((size_t)(b * SDIM + qr)) * DDIM + h * HDIM + n * 16 + lr] =
            (__bf16)(o[n][r] * rl);
    }
  }
}

// ---------------------------------------------------------------- launch
extern "C" void kernel_launch(void* const* d_in, const int* in_sizes, int n_in,
                              void* d_out, int out_size, void* d_ws, size_t ws_size,
                              hipStream_t stream) {
  const float* x  = (const float*)d_in[0];
  const float* wq = (const float*)d_in[1];
  const float* wk = (const float*)d_in[2];
  const float* wv = (const float*)d_in[3];
  const float* wo = (const float*)d_in[4];

  char* ws = (char*)d_ws;
  const size_t MB = 1024 * 1024;
  bf16* xb   = (bf16*)(ws + 0);        // 8 MB (reused as vtb after QKV GEMM)
  bf16* wqb  = (bf16*)(ws + 8 * MB);   // wq,wk,wv contiguous for grid.z
  bf16* wkb  = (bf16*)(ws + 10 * MB);
  bf16* wvb  = (bf16*)(ws + 12 * MB);
  bf16* wob  = (bf16*)(ws + 14 * MB);
  bf16* qb   = (bf16*)(ws + 16 * MB);  // 8 MB each
  bf16* kb   = (bf16*)(ws + 24 * MB);
  bf16* vb   = (bf16*)(ws + 32 * MB);
  bf16* ob   = (bf16*)(ws + 40 * MB);  // 8 MB
  float* cosT = (float*)(ws + 48 * MB);
  float* sinT = (float*)(ws + 49 * MB);
  bf16* vtb  = xb;  // V transposed [bh][64][S], overwrites xb (free after QKV GEMM)
  (void)wkb; (void)wvb;

  const int NX = BDIM * SDIM * DDIM;  // 4194304
  const int NW = DDIM * DDIM;         // 1048576

  cvt_bf16<<<NX / 4 / 256, 256, 0, stream>>>(x, xb, NX / 4);
  cvt_bf16<<<NW / 4 / 256, 256, 0, stream>>>(wq, wqb, NW / 4);
  cvt_bf16<<<NW / 4 / 256, 256, 0, stream>>>(wk, wkb, NW / 4);
  cvt_bf16<<<NW / 4 / 256, 256, 0, stream>>>(wv, wvb, NW / 4);
  cvt_bf16<<<NW / 4 / 256, 256, 0, stream>>>(wo, wob, NW / 4);
  rope_table<<<(SDIM * 32) / 256, 256, 0, stream>>>(cosT, sinT);
  gemm_bt<0><<<dim3(8, 32, 3), 256, 0, stream>>>(xb, wqb, (void*)qb);
  rope_apply<<<(32 * SDIM * 32) / 256, 256, 0, stream>>>(qb, kb, cosT, sinT);
  transpose_v<<<dim3(SDIM / 32, 32), 256, 0, stream>>>((const unsigned short*)vb,
                                                       (unsigned short*)vtb);
  attn_fwd<<<dim3(16, 32), 256, 0, stream>>>(qb, kb, vtb, ob);
  gemm_bt<1><<<dim3(8, 32, 1), 256, 0, stream>>>(ob, wob, d_out);
}

// Round 4
// 148.911 us; speedup vs baseline: 1.7414x; 1.1653x over previous
//
#include <hip/hip_runtime.h>
#include <hip/hip_bf16.h>
#include <cstdint>
#include <cstddef>

// Problem constants
#define BDIM 2
#define SDIM 2048
#define DDIM 1024
#define HN   16
#define HDIM 64

using bf16 = __bf16;
typedef __attribute__((ext_vector_type(8))) __bf16 bf16x8;
typedef __attribute__((ext_vector_type(4))) __bf16 bf16x4;
typedef __attribute__((ext_vector_type(8))) unsigned short ushort8;
typedef __attribute__((ext_vector_type(4))) float  f32x4;

#define MFMA16(a, b, c) __builtin_amdgcn_mfma_f32_16x16x32_bf16((a), (b), (c), 0, 0, 0)

#define ASYNC16(g, l)                                                          \
  __builtin_amdgcn_global_load_lds(                                            \
      (const __attribute__((address_space(1))) void*)(g),                      \
      (__attribute__((address_space(3))) void*)(l), 16, 0, 0)

// scale folded into Q at rope time: 1/sqrt(64) * log2(e)  (softmax in exp2 domain)
#define QSCALE 0.1803368801111204f

// ---------------------------------------------------------------- conversions
__global__ __launch_bounds__(256) void cvt_bf16(const float* __restrict__ src,
                                                bf16* __restrict__ dst, int n4) {
  int i = blockIdx.x * 256 + threadIdx.x;
  if (i < n4) {
    float4 v = ((const float4*)src)[i];
    bf16x4 o = {(__bf16)v.x, (__bf16)v.y, (__bf16)v.z, (__bf16)v.w};
    *(bf16x4*)(dst + (size_t)i * 4) = o;
  }
}

struct Ptr4 { const float* p[4]; };
// 4 weight matrices -> contiguous bf16 (wq,wk,wv,wo), grid.y = segment
__global__ __launch_bounds__(256) void cvt_w(Ptr4 srcs, bf16* __restrict__ dst) {
  const int seg = blockIdx.y;
  const float* src = srcs.p[seg];
  int i = blockIdx.x * 256 + threadIdx.x;  // < NW/4
  float4 v = ((const float4*)src)[i];
  bf16x4 o = {(__bf16)v.x, (__bf16)v.y, (__bf16)v.z, (__bf16)v.w};
  *(bf16x4*)(dst + (size_t)seg * (DDIM * DDIM) + (size_t)i * 4) = o;
}

// ---------------------------------------------------------------- rope table
__global__ __launch_bounds__(256) void rope_table(float* __restrict__ cosT,
                                                  float* __restrict__ sinT) {
  int i = blockIdx.x * 256 + threadIdx.x;  // SDIM*32 threads
  int s = i >> 5, j = i & 31;
  float inv = powf(10000.f, -(float)j * (1.f / 32.f));
  float a = (float)s * inv;
  float sn, c;
  sincosf(a, &sn, &c);
  cosT[s * 64 + j]      = c;
  cosT[s * 64 + j + 32] = c;
  sinT[s * 64 + j]      = sn;
  sinT[s * 64 + j + 32] = sn;
}

// ---------------------------------------------------------------- rope apply (in-place; q also pre-scaled)
__global__ __launch_bounds__(256) void rope_apply(bf16* __restrict__ q,
                                                  bf16* __restrict__ k,
                                                  const float* __restrict__ cosT,
                                                  const float* __restrict__ sinT) {
  int i = blockIdx.x * 256 + threadIdx.x;  // 32*SDIM*32 threads
  int j = i & 31;
  int s = (i >> 5) & (SDIM - 1);
  int bh = i >> 16;  // SDIM*32 == 1<<16
  size_t base = ((size_t)bh * SDIM + s) * HDIM;
  float c = cosT[s * 64 + j], sn = sinT[s * 64 + j];
  float a = (float)q[base + j], b2 = (float)q[base + j + 32];
  q[base + j]      = (__bf16)((a * c - b2 * sn) * QSCALE);
  q[base + j + 32] = (__bf16)((b2 * c + a * sn) * QSCALE);
  a = (float)k[base + j]; b2 = (float)k[base + j + 32];
  k[base + j]      = (__bf16)(a * c - b2 * sn);
  k[base + j + 32] = (__bf16)(b2 * c + a * sn);
}

// ---------------------------------------------------------------- V transpose: [bh][s][64] -> [bh][64][s]
__global__ __launch_bounds__(256) void transpose_v(const unsigned short* __restrict__ v,
                                                   unsigned short* __restrict__ vt) {
  const int bh = blockIdx.y;
  const int s_base = blockIdx.x * 32 + (threadIdx.x >> 6) * 8;
  const int d = threadIdx.x & 63;
  const unsigned short* src = v + ((size_t)bh * SDIM + s_base) * HDIM + d;
  ushort8 o;
#pragma unroll
  for (int j = 0; j < 8; ++j) o[j] = src[(size_t)j * HDIM];  // coalesced: 64 lanes x 2B = 128B/line
  *(ushort8*)(vt + ((size_t)bh * HDIM + d) * SDIM + s_base) = o;
}

// ---------------------------------------------------------------- GEMM  C = A * B^T
// A: [4096][1024] bf16 row-major, Bw: [1024][1024] bf16 row-major (rows = out features)
// MODE 0: write bf16 to [B][H][S][HD] (QKV), blockIdx.z selects weight/output
// MODE 1: write fp32 row-major [4096][1024]
template <int MODE>
__global__ __launch_bounds__(256) void gemm_bt(const bf16* __restrict__ A,
                                               const bf16* __restrict__ B0,
                                               void* __restrict__ C0) {
  constexpr int K = 1024;
  __shared__ __align__(16) bf16 As[128 * 64];
  __shared__ __align__(16) bf16 Bs[128 * 64];
  const int tid = threadIdx.x;
  const int l = tid & 63, w = tid >> 6;
  const int wr = w >> 1, wc = w & 1;
  const int lr = l & 15, lg = l >> 4;
  const int bm = blockIdx.y * 128;
  const int bn = blockIdx.x * 128;
  const bf16* Bw = B0 + (size_t)blockIdx.z * (1024 * 1024);

  f32x4 acc[4][4] = {};

  for (int k0 = 0; k0 < K; k0 += 64) {
    __syncthreads();
#pragma unroll
    for (int i = 0; i < 4; ++i) {
      int idx = i * 2048 + tid * 8;
      int row = idx >> 6, col = idx & 63;
      ASYNC16(A + (size_t)(bm + row) * K + (k0 + col), As + idx);
      ASYNC16(Bw + (size_t)(bn + row) * K + (k0 + col), Bs + idx);
    }
    __syncthreads();
#pragma unroll
    for (int c = 0; c < 2; ++c) {
      bf16x8 af[4], bfr[4];
#pragma unroll
      for (int m = 0; m < 4; ++m)
        af[m] = *(const bf16x8*)(As + (wr * 64 + m * 16 + lr) * 64 + c * 32 + lg * 8);
#pragma unroll
      for (int n = 0; n < 4; ++n)
        bfr[n] = *(const bf16x8*)(Bs + (wc * 64 + n * 16 + lr) * 64 + c * 32 + lg * 8);
      __builtin_amdgcn_s_setprio(1);
#pragma unroll
      for (int m = 0; m < 4; ++m)
#pragma unroll
        for (int n = 0; n < 4; ++n)
          acc[m][n] = MFMA16(af[m], bfr[n], acc[m][n]);
      __builtin_amdgcn_s_setprio(0);
    }
  }

#pragma unroll
  for (int m = 0; m < 4; ++m) {
#pragma unroll
    for (int n = 0; n < 4; ++n) {
#pragma unroll
      for (int r = 0; r < 4; ++r) {
        int row = bm + wr * 64 + m * 16 + lg * 4 + r;
        int col = bn + wc * 64 + n * 16 + lr;
        float v = acc[m][n][r];
        if constexpr (MODE == 0) {
          bf16* C = (bf16*)C0 + (size_t)blockIdx.z * ((size_t)BDIM * SDIM * DDIM);
          size_t off = (((size_t)(row >> 11) * HN + (col >> 6)) * SDIM + (row & (SDIM - 1))) * HDIM + (col & 63);
          C[off] = (__bf16)v;
        } else {
          ((float*)C0)[(size_t)row * DDIM + col] = v;
        }
      }
    }
  }
}

// ---------------------------------------------------------------- flash attention (causal, balanced, swapped-QK^T)
// Q/K: [B*H][S][HD] bf16 (roped, Q pre-scaled by 1/8*log2e). Vt: [B*H][HD][S].
// Output: [B][S][D] bf16 row-major.
// Work remap (T1): head = lin&31 so lin%8 == head%8 -> each XCD serves 4 heads,
// K/V working set 2 MB < 4 MB L2 (was: 32 heads/XCD, pure HBM re-reads).
// Block = 4 waves, q-tile pair (qp, 31-qp): exactly 33 KV stages. Double-buffered
// K/V staging (1 barrier per tile), per-lane source pointers hoisted out of loop.
__global__ __launch_bounds__(256) void attn_fwd(const bf16* __restrict__ qg,
                                                const bf16* __restrict__ kg,
                                                const bf16* __restrict__ vtg,
                                                bf16* __restrict__ og) {
  __shared__ __align__(16) bf16 Ks[2][8 * 512];
  __shared__ __align__(16) bf16 Vs[2][8 * 512];
  __shared__ __align__(16) bf16 Pl[4][16 * 72];

  const int tid = threadIdx.x;
  const int l = tid & 63, w = tid >> 6;
  const int lr = l & 15, lg = l >> 4;
  const int lin = blockIdx.x + (blockIdx.y << 4);
  const int bh = lin & 31;   // head-major: fixes XCD L2 locality
  const int qp = lin >> 5;   // 0..15
  const size_t hb = (size_t)bh * SDIM * HDIM;
  const bf16* Q  = qg + hb;
  const bf16* Kp = kg + hb;
  const bf16* Vp = vtg + hb;  // [64][SDIM]
  const int b = bh >> 4, h = bh & 15;
  bf16* Pw = &Pl[w][0];

  const int mm0 = 2 * w, mm1 = 2 * w + 1;
  const int f0 = mm0 & 3, c0 = mm0 >> 2;
  const int f1 = mm1 & 3, c1 = mm1 >> 2;
  bf16* const kd0_0 = Ks[0] + mm0 * 512 + l * 8;
  bf16* const kd1_0 = Ks[0] + mm1 * 512 + l * 8;
  bf16* const vd0_0 = Vs[0] + mm0 * 512 + l * 8;
  bf16* const vd1_0 = Vs[0] + mm1 * 512 + l * 8;

  for (int phase = 0; phase < 2; ++phase) {
    const int qt = phase ? (31 - qp) : qp;
    const int q0 = qt * 64;

    bf16x8 qf[2];
#pragma unroll
    for (int c = 0; c < 2; ++c)
      qf[c] = *(const bf16x8*)(Q + (size_t)(q0 + w * 16 + lr) * HDIM + c * 32 + lg * 8);

    f32x4 o[4] = {};
    float m = -3e38f, lsum = 0.f;

    // per-lane source pointers, advanced by constant stride per tile
    const bf16* kN0 = Kp + (size_t)(f0 * 16 + lr) * HDIM + c0 * 32 + lg * 8;
    const bf16* kN1 = Kp + (size_t)(f1 * 16 + lr) * HDIM + c1 * 32 + lg * 8;
    const bf16* vN0 = Vp + (size_t)(f0 * 16 + lr) * SDIM + c0 * 32 + lg * 8;
    const bf16* vN1 = Vp + (size_t)(f1 * 16 + lr) * SDIM + c1 * 32 + lg * 8;

    // prologue: stage tile 0 into buffer 0
    ASYNC16(kN0, kd0_0); kN0 += 64 * HDIM;
    ASYNC16(kN1, kd1_0); kN1 += 64 * HDIM;
    ASYNC16(vN0, vd0_0); vN0 += 64;
    ASYNC16(vN1, vd1_0); vN1 += 64;
    __syncthreads();

    for (int t = 0; t <= qt; ++t) {
      const int cur = t & 1;
      // issue next tile's staging into the other buffer (hidden under compute)
      if (t < qt) {
        bf16* kd = Ks[cur ^ 1];
        bf16* vd = Vs[cur ^ 1];
        ASYNC16(kN0, kd + mm0 * 512 + l * 8); kN0 += 64 * HDIM;
        ASYNC16(kN1, kd + mm1 * 512 + l * 8); kN1 += 64 * HDIM;
        ASYNC16(vN0, vd + mm0 * 512 + l * 8); vN0 += 64;
        ASYNC16(vN1, vd + mm1 * 512 + l * 8); vN1 += 64;
      }

      const bool diag = (t == qt);
      const int fLim = diag ? w : 3;

      // swapped QK^T: sc[f] col=q-row(lr), row=key(f*16+lg*4+r)
      f32x4 sc[4] = {};
      __builtin_amdgcn_s_setprio(1);
#pragma unroll
      for (int c = 0; c < 2; ++c)
#pragma unroll
        for (int f = 0; f < 4; ++f)
          if (f <= fLim) {
            bf16x8 kfr = *(const bf16x8*)(Ks[cur] + (c * 4 + f) * 512 + l * 8);
            sc[f] = MFMA16(kfr, qf[c], sc[f]);
          }
      __builtin_amdgcn_s_setprio(0);

      if (diag) {
#pragma unroll
        for (int f = 0; f < 4; ++f)
#pragma unroll
          for (int r = 0; r < 4; ++r) {
            if (f > w)
              sc[f][r] = -3e38f;
            else if (f == w)
              sc[f][r] = (lg * 4 + r <= lr) ? sc[f][r] : -3e38f;
          }
      }

      // row max: 16 in-register + 2 cross-lane
      float mx = -3e38f;
#pragma unroll
      for (int f = 0; f < 4; ++f)
#pragma unroll
        for (int r = 0; r < 4; ++r) mx = fmaxf(mx, sc[f][r]);
      mx = fmaxf(mx, __shfl_xor(mx, 16));
      mx = fmaxf(mx, __shfl_xor(mx, 32));

      // defer-max: rescale only when the running max grew materially
      if (!__all(mx - m <= 8.f)) {
        float mnew = fmaxf(m, mx);
        float corr = exp2f(m - mnew);
        m = mnew;
        lsum *= corr;
        float cb[4];
#pragma unroll
        for (int r = 0; r < 4; ++r) cb[r] = __shfl(corr, lg * 4 + r);
#pragma unroll
        for (int n = 0; n < 4; ++n)
#pragma unroll
          for (int r = 0; r < 4; ++r) o[n][r] *= cb[r];
      }

      // P = exp2(sc - m); packed b64 stores to Pl[q][key]
      float rs = 0.f;
#pragma unroll
      for (int f = 0; f < 4; ++f) {
        float p0 = exp2f(sc[f][0] - m);
        float p1 = exp2f(sc[f][1] - m);
        float p2 = exp2f(sc[f][2] - m);
        float p3 = exp2f(sc[f][3] - m);
        rs += (p0 + p1) + (p2 + p3);
        bf16x4 pv = {(__bf16)p0, (__bf16)p1, (__bf16)p2, (__bf16)p3};
        *(bf16x4*)(Pw + lr * 72 + f * 16 + lg * 4) = pv;
      }
      rs += __shfl_xor(rs, 16);
      rs += __shfl_xor(rs, 32);
      lsum += rs;

      // PV (skip fully-zero key chunks on the diagonal tile)
      const int cLim = diag ? (w >> 1) : 1;
      __builtin_amdgcn_s_setprio(1);
#pragma unroll
      for (int c = 0; c < 2; ++c)
        if (c <= cLim) {
          bf16x8 pf = *(const bf16x8*)(Pw + lr * 72 + c * 32 + lg * 8);
#pragma unroll
          for (int n = 0; n < 4; ++n) {
            bf16x8 vfr = *(const bf16x8*)(Vs[cur] + (c * 4 + n) * 512 + l * 8);
            o[n] = MFMA16(pf, vfr, o[n]);
          }
        }
      __builtin_amdgcn_s_setprio(0);

      __syncthreads();  // buf[cur] consumed by all; buf[cur^1] staged+visible
    }

    // epilogue: broadcast lsum from softmax layout (per lr) to O layout (per lg*4+r)
    float lb[4];
#pragma unroll
    for (int r = 0; r < 4; ++r) lb[r] = __shfl(lsum, lg * 4 + r);
#pragma unroll
    for (int r = 0; r < 4; ++r) {
      float rl = 1.f / lb[r];
      int qr = q0 + 16 * w + lg * 4 + r;
#pragma unroll
      for (int n = 0; n < 4; ++n)
        og[((size_t)(b * SDIM + qr)) * DDIM + h * HDIM + n * 16 + lr] =
            (__bf16)(o[n][r] * rl);
    }
  }
}

// ---------------------------------------------------------------- launch
extern "C" void kernel_launch(void* const* d_in, const int* in_sizes, int n_in,
                              void* d_out, int out_size, void* d_ws, size_t ws_size,
                              hipStream_t stream) {
  const float* x  = (const float*)d_in[0];
  const float* wq = (const float*)d_in[1];
  const float* wk = (const float*)d_in[2];
  const float* wv = (const float*)d_in[3];
  const float* wo = (const float*)d_in[4];

  char* ws = (char*)d_ws;
  const size_t MB = 1024 * 1024;
  bf16* xb   = (bf16*)(ws + 0);        // 8 MB (reused as vtb after QKV GEMM)
  bf16* wqb  = (bf16*)(ws + 8 * MB);   // wq,wk,wv,wo contiguous
  bf16* wob  = (bf16*)(ws + 14 * MB);
  bf16* qb   = (bf16*)(ws + 16 * MB);  // 8 MB each
  bf16* kb   = (bf16*)(ws + 24 * MB);
  bf16* vb   = (bf16*)(ws + 32 * MB);
  bf16* ob   = (bf16*)(ws + 40 * MB);  // 8 MB
  float* cosT = (float*)(ws + 48 * MB);
  float* sinT = (float*)(ws + 49 * MB);
  bf16* vtb  = xb;  // V transposed [bh][64][S], overwrites xb (free after QKV GEMM)

  const int NX = BDIM * SDIM * DDIM;  // 4194304
  const int NW = DDIM * DDIM;         // 1048576

  cvt_bf16<<<NX / 4 / 256, 256, 0, stream>>>(x, xb, NX / 4);
  Ptr4 wsrc{{wq, wk, wv, wo}};
  cvt_w<<<dim3(NW / 4 / 256, 4), 256, 0, stream>>>(wsrc, wqb);
  rope_table<<<(SDIM * 32) / 256, 256, 0, stream>>>(cosT, sinT);
  gemm_bt<0><<<dim3(8, 32, 3), 256, 0, stream>>>(xb, wqb, (void*)qb);
  rope_apply<<<(32 * SDIM * 32) / 256, 256, 0, stream>>>(qb, kb, cosT, sinT);
  transpose_v<<<dim3(SDIM / 32, 32), 256, 0, stream>>>((const unsigned short*)vb,
                                                       (unsigned short*)vtb);
  attn_fwd<<<dim3(16, 32), 256, 0, stream>>>(qb, kb, vtb, ob);
  gemm_bt<1><<<dim3(8, 32, 1), 256, 0, stream>>>(ob, wob, d_out);
}